// Round 12
// baseline (756.376 us; speedup 1.0000x reference)
//
#include <hip/hip_runtime.h>

// PatternLearner on MI355X (gfx950). Inputs fp32, outputs fp32.
// d_out = [output0 (N*H) | output1=pattern (N*H)] fp32.
// Scratch-in-d_out: patb(bf16) bytes [0,12.58M), w1t..w2td bytes [12.58M,22.02M)
// — inside output0's byte range, overwritten only by the final exp0.
// R11/R12 (R12 = R11 resubmitted after infra fail):
// (a) dist_topk v10 — transcendental-free selection filter: global sigmin
// (atomicMin in prep_mem), filter = `arg < argT[ip]` with argT cached per
// ip-group, recomputed (1 exp2) only when the group threshold changes; a2/iv
// hoisted to registers (no per-element LDS reads); merge rejects over-passes.
// (b) gemm_bt reverted to m97-exact: single 32KB buffer, 2-barrier K-loop,
// launch_bounds(256,3) (3 blocks/CU implicit overlap, m114).

#define N_TOK 8192
#define HDIM  768
#define H2DIM 1536
#define PMEM  8192
#define KTOP  16
#define DSPLIT 16
#define CHUNK_N 128
#define DCHUNKS (PMEM/DSPLIT/CHUNK_N)   // 4
#define BKD 64
#define KSTEPS (HDIM/BKD)               // 12
#define NLIST (DSPLIT*2)                // 32 sorted lists per token

typedef __attribute__((ext_vector_type(8))) short bf16x8;   // 8 bf16 = 4 VGPRs
typedef __attribute__((ext_vector_type(4))) float f32x4;
typedef unsigned short u16;
typedef unsigned int   u32;

__device__ __forceinline__ float bf2f(u16 u){ return __uint_as_float(((u32)u)<<16); }
__device__ __forceinline__ u16 f2bf(float f){
  u32 x = __float_as_uint(f);
  return (u16)((x + 0x7FFFu + ((x>>16)&1u)) >> 16);   // RNE
}
__device__ __forceinline__ void lds_dma16(const void* g, void* l){
  __builtin_amdgcn_global_load_lds(
      (const __attribute__((address_space(1))) void*)g,
      (__attribute__((address_space(3))) void*)l, 16, 0, 0);
}

__device__ __forceinline__ float block_sum(float s){
  #pragma unroll
  for (int o=32;o;o>>=1) s += __shfl_xor(s,o);
  __shared__ float ps[4];
  int tid = threadIdx.x;
  if ((tid&63)==0) ps[tid>>6] = s;
  __syncthreads();
  return ps[0]+ps[1]+ps[2]+ps[3];
}

// ---- log0: v = atanh(nc)*x/nc. fp32 in, bf16 out ----
__global__ __launch_bounds__(256) void log0_rows(const float* __restrict__ in, u16* __restrict__ out){
  int r = blockIdx.x, tid = threadIdx.x;
  size_t ro = (size_t)r*HDIM;
  float v0=in[ro+tid], v1=in[ro+tid+256], v2=in[ro+tid+512];
  float s = block_sum(v0*v0+v1*v1+v2*v2);
  float n = sqrtf(s);
  float nc = fminf(fmaxf(n, 1e-5f), 1.0f-1e-5f);
  float sc = atanhf(nc)/nc;
  u16* orow = out + ro;
  orow[tid]=f2bf(v0*sc); orow[tid+256]=f2bf(v1*sc); orow[tid+512]=f2bf(v2*sc);
}

// ---- exp0: y = tanh(nm)*x/nm. bf16 in; fp32 out (+optional bf16 copy, a2/iva)
__global__ __launch_bounds__(256) void exp0_rows(const u16* __restrict__ in, float* __restrict__ outf,
                                                 u16* outb, float* a2p, float* ivp){
  int r = blockIdx.x, tid = threadIdx.x;
  const u16* row = in + (size_t)r*HDIM;
  float v0=bf2f(row[tid]), v1=bf2f(row[tid+256]), v2=bf2f(row[tid+512]);
  float s = block_sum(v0*v0+v1*v1+v2*v2);
  float n = sqrtf(s);
  float nm = fmaxf(n, 1e-5f);
  float sc = tanhf(nm)/nm;
  size_t ro = (size_t)r*HDIM;
  outf[ro+tid]=v0*sc; outf[ro+tid+256]=v1*sc; outf[ro+tid+512]=v2*sc;
  if (outb != nullptr){
    outb[ro+tid]=f2bf(v0*sc); outb[ro+tid+256]=f2bf(v1*sc); outb[ro+tid+512]=f2bf(v2*sc);
  }
  if (a2p != nullptr && tid==0){
    float a2 = fminf(sc*sc*s, 1.0f-1e-5f);
    a2p[r] = a2; ivp[r] = 1.0f/(1.0f-a2);
  }
}

// ---- memory prep: memb(bf16), pmeta = {b2, 1/(1-b2), sigmoid(imp), 0};
//      sgm = global min of sigmoid(imp) (uint-bits atomicMin, positive floats)
__global__ __launch_bounds__(256) void prep_mem(const float* __restrict__ mem, const float* __restrict__ imp,
                                                u16* __restrict__ memb, float4* __restrict__ pmeta,
                                                unsigned int* sgm){
  int p = blockIdx.x, tid = threadIdx.x;
  size_t ro = (size_t)p*HDIM;
  float v0=mem[ro+tid], v1=mem[ro+tid+256], v2=mem[ro+tid+512];
  memb[ro+tid]=f2bf(v0); memb[ro+tid+256]=f2bf(v1); memb[ro+tid+512]=f2bf(v2);
  float s = block_sum(v0*v0+v1*v1+v2*v2);
  if (tid==0){
    float b2 = fminf(s, 1.0f-1e-5f);
    float4 m; m.x=b2; m.y=1.0f/(1.0f-b2); m.z=1.0f/(1.0f+__expf(-imp[p])); m.w=0.f;
    pmeta[p]=m;
    atomicMin(sgm, __float_as_uint(m.z));
  }
}

// ---- LayerNorm + exact gelu over rows of 1536; in-place safe ----
__global__ __launch_bounds__(256) void ln_gelu(const u16* __restrict__ in, const float* __restrict__ g,
                                               const float* __restrict__ be, u16* __restrict__ out){
  int r = blockIdx.x, tid = threadIdx.x;
  const u16* row = in + (size_t)r*H2DIM;
  float h[6]; float s=0.f, s2=0.f;
  #pragma unroll
  for (int j=0;j<6;j++){ float v=bf2f(row[tid+256*j]); h[j]=v; s+=v; s2+=v*v; }
  #pragma unroll
  for (int o=32;o;o>>=1){ s += __shfl_xor(s,o); s2 += __shfl_xor(s2,o); }
  __shared__ float ps[4], ps2[4];
  if ((tid&63)==0){ ps[tid>>6]=s; ps2[tid>>6]=s2; }
  __syncthreads();
  s = ps[0]+ps[1]+ps[2]+ps[3]; s2 = ps2[0]+ps2[1]+ps2[2]+ps2[3];
  float mu  = s*(1.0f/H2DIM);
  float var = fmaxf(s2*(1.0f/H2DIM) - mu*mu, 0.0f);
  float rstd = rsqrtf(var + 1e-5f);
  u16* orow = out + (size_t)r*H2DIM;
  #pragma unroll
  for (int j=0;j<6;j++){
    int c = tid+256*j;
    float y = (h[j]-mu)*rstd*g[c] + be[c];
    float ge = 0.5f*y*(1.0f + erff(y*0.70710678118654752f));
    orow[c] = f2bf(ge);
  }
}

// ---- GEMM: C[M,N] = A[M,K]*BT[N,K]^T + bias; bf16 in/out, fp32 acc/bias ----
// m97-exact: 128x128 tile, BK=64, single 32KB buffer, 2 barriers/K-step,
// launch_bounds(256,3) -> 3 blocks/CU (implicit wave-level overlap, m114).
__global__ __launch_bounds__(256,3) void gemm_bt(
    const u16* __restrict__ A, const u16* __restrict__ B,
    const float* __restrict__ bias, u16* __restrict__ C,
    int M, int Nn, int Kk)
{
  __shared__ u16 As[128*64];   // 16 KB
  __shared__ u16 Bs[128*64];   // 16 KB
  const int tid = threadIdx.x;
  const int m0 = blockIdx.y*128, n0 = blockIdx.x*128;
  const int wave = tid>>6, lane = tid&63;
  const int wm = (wave>>1)*64, wn = (wave&1)*64;
  const int col = lane&15, quad = lane>>4;

  int sr[4], sk[4];
  #pragma unroll
  for (int j=0;j<4;j++){
    int c = j*256 + wave*64 + lane;
    int r = c>>3, kc = c&7;
    sr[j] = r; sk[j] = (kc ^ (r&7))*8;
  }

  f32x4 acc[4][4] = {};
  for (int k0=0; k0<Kk; k0+=64){
    __syncthreads();                       // tiles free (prev MFMA reads done)
    #pragma unroll
    for (int j=0;j<4;j++){
      lds_dma16(A + (size_t)(m0+sr[j])*Kk + k0 + sk[j], As + (size_t)(j*256 + wave*64)*8);
      lds_dma16(B + (size_t)(n0+sr[j])*Kk + k0 + sk[j], Bs + (size_t)(j*256 + wave*64)*8);
    }
    __syncthreads();                       // vmcnt(0) drained before barrier
    #pragma unroll
    for (int kk=0;kk<2;kk++){
      const int kq = kk*4 + quad;
      bf16x8 af[4], bfr[4];
      #pragma unroll
      for (int i=0;i<4;i++){
        int ar = wm + i*16 + col;
        af[i]  = *(const bf16x8*)&As[ar*64 + ((kq ^ (ar&7))*8)];
      }
      #pragma unroll
      for (int j=0;j<4;j++){
        int br = wn + j*16 + col;
        bfr[j] = *(const bf16x8*)&Bs[br*64 + ((kq ^ (br&7))*8)];
      }
      #pragma unroll
      for (int i=0;i<4;i++)
        #pragma unroll
        for (int j=0;j<4;j++)
          acc[i][j] = __builtin_amdgcn_mfma_f32_16x16x32_bf16(af[i], bfr[j], acc[i][j], 0,0,0);
    }
  }
  #pragma unroll
  for (int j=0;j<4;j++){
    int cc = n0 + wn + j*16 + col;
    float bv = bias[cc];
    #pragma unroll
    for (int i=0;i<4;i++){
      int rbase = m0 + wm + i*16 + quad*4;
      #pragma unroll
      for (int rr=0;rr<4;rr++)
        C[(size_t)(rbase+rr)*Nn + cc] = f2bf(acc[i][j][rr] + bv);
    }
  }
}

// ---- transpose fp32 -> bf16 ----
__global__ __launch_bounds__(256) void transpose_f2b(const float* __restrict__ in, u16* __restrict__ out,
                                                     int R, int Ccols){
  __shared__ float tile[32][33];
  int tx = threadIdx.x & 31, ty = threadIdx.x >> 5;
  int c0 = blockIdx.x*32, r0 = blockIdx.y*32;
  #pragma unroll
  for (int i=0;i<32;i+=8) tile[ty+i][tx] = in[(size_t)(r0+ty+i)*Ccols + c0+tx];
  __syncthreads();
  #pragma unroll
  for (int i=0;i<32;i+=8) out[(size_t)(c0+ty+i)*R + r0+tx] = f2bf(tile[tx][ty+i]);
}

// ---- dist_topk v10: 128x128 tile @ DSPLIT=16, cached arg-domain filter ----
// grid (N_TOK/128, DSPLIT) = (64,16) = 1024 blocks. Wave (wm,wn) owns 64x64.
// Selection filter (no transcendentals on the fast path): d >= log2(arg)*sigmin
// for arg>=1, so reject iff arg >= argT where argT = 2^(thr*inv_sigmin)*1.0001
// (cached per ip-group of 4 tokens, thr = max of the 4 token thresholds;
// recomputed only when thr changes; empty list -> argT=inf; argT>=1.0000002 so
// arg<1 always passes). Survivors get the exact acosh path; merge's v<worst
// rejects any over-passes. a2/2*iva live in registers (no per-element LDS).
// packed key = (log2dist_bits & ~0x1FFF) | pattern_idx.
__global__ __launch_bounds__(256,3) void dist_topk(
    const u16* __restrict__ patb, const u16* __restrict__ memb,
    const float* __restrict__ a2f, const float* __restrict__ iva,
    const float4* __restrict__ pmeta, const unsigned int* __restrict__ sgm,
    u32* __restrict__ plist)
{
  __shared__ char usm[16640 + 16384];    // union{Atile 16K, cand 16.64K} + Btile 16K
  u16* Atile = (u16*)usm;                // 128 x 64, swizzled
  u16* Btile = (u16*)(usm + 16640);      // 128 x 64, swizzled
  u32* candb = (u32*)usm;                // cand[wave][col][tt] pitch 65
  __shared__ u32 masks[4][64];
  const int tid = threadIdx.x;
  const int wave = tid>>6, lane = tid&63;
  const int col = lane&15, quad = lane>>4;
  const int wm = (wave>>1)*64, wn = (wave&1)*64;
  const int t0 = blockIdx.x*128;
  const int s  = blockIdx.y;
  const int pb0 = s*(PMEM/DSPLIT);       // 512-pattern slice
  const float invsg = 1.0f/__uint_as_float(*sgm);
  // per-lane token invariants in registers (token tt = wm + ip*16 + quad*4 + rr)
  float a2v[16], cv[16];
  #pragma unroll
  for (int ip=0;ip<4;ip++)
    #pragma unroll
    for (int rr=0;rr<4;rr++){
      int tg = t0 + wm + ip*16 + quad*4 + rr;
      a2v[ip*4+rr] = a2f[tg];
      cv[ip*4+rr]  = 2.0f*iva[tg];
    }
  u32 lst[16];
  #pragma unroll
  for (int j=0;j<16;j++) lst[j] = 0xFFFFFFFFu;
  u32 thrC[4]; float argT[4];
  #pragma unroll
  for (int j=0;j<4;j++){ thrC[j] = 0xFFFFFFFFu; argT[j] = __builtin_inff(); }
  // staging coords (A and B share the formula: 128x64 tiles)
  int sr[4], sk[4];
  #pragma unroll
  for (int j=0;j<4;j++){
    int c = j*256 + wave*64 + lane;
    int r = c>>3, kc = c&7;
    sr[j] = r; sk[j] = (kc ^ (r&7))*8;
  }
  u32* candw = candb + wave*(16*65);

  for (int nc=0; nc<DCHUNKS; nc++){
    const int pbase = pb0 + nc*CHUNK_N;
    f32x4 acc[4][4] = {};
    for (int ks=0; ks<KSTEPS; ks++){
      const int k0 = ks*BKD;
      __syncthreads();                      // tiles free (prev MFMA / selection done)
      #pragma unroll
      for (int j=0;j<4;j++){
        lds_dma16(patb + (size_t)(t0+sr[j])*HDIM + k0 + sk[j], Atile + (size_t)(j*256 + wave*64)*8);
        lds_dma16(memb + (size_t)(pbase+sr[j])*HDIM + k0 + sk[j], Btile + (size_t)(j*256 + wave*64)*8);
      }
      __syncthreads();                      // vmcnt(0) drained before barrier
      #pragma unroll
      for (int kk=0;kk<2;kk++){
        const int kq = kk*4 + quad;
        bf16x8 af[4], bfr[4];
        #pragma unroll
        for (int i=0;i<4;i++){
          int ar = wm + i*16 + col;
          af[i] = *(const bf16x8*)&Atile[ar*64 + ((kq ^ (ar&7))*8)];
        }
        #pragma unroll
        for (int j=0;j<4;j++){
          int br = wn + j*16 + col;
          bfr[j] = *(const bf16x8*)&Btile[br*64 + ((kq ^ (br&7))*8)];
        }
        #pragma unroll
        for (int i=0;i<4;i++)
          #pragma unroll
          for (int j=0;j<4;j++)
            acc[i][j] = __builtin_amdgcn_mfma_f32_16x16x32_bf16(af[i], bfr[j], acc[i][j], 0,0,0);
      }
    }
    __syncthreads();   // all tile reads done before cand (union) is written
    // selection: 4 passes of 16 patterns (p = acc's j index)
    #pragma unroll
    for (int p=0;p<4;p++){
      // refresh cached group thresholds (thr = max over the 4 tokens of a group)
      #pragma unroll
      for (int ip=0;ip<4;ip++){
        u32 k0v = (u32)__shfl((int)lst[15], ip*16 + quad*4 + 0);
        u32 k1v = (u32)__shfl((int)lst[15], ip*16 + quad*4 + 1);
        u32 k2v = (u32)__shfl((int)lst[15], ip*16 + quad*4 + 2);
        u32 k3v = (u32)__shfl((int)lst[15], ip*16 + quad*4 + 3);
        u32 mx01 = k0v > k1v ? k0v : k1v;
        u32 mx23 = k2v > k3v ? k2v : k3v;
        u32 mx = mx01 > mx23 ? mx01 : mx23;
        if (mx != thrC[ip]){
          thrC[ip] = mx;
          argT[ip] = (mx == 0xFFFFFFFFu) ? __builtin_inff()
                   : fmaxf(exp2f(__uint_as_float(mx & 0xFFFFE000u)*invsg)*1.0001f, 1.0000002f);
        }
      }
      const int pglob = pbase + wn + p*16 + col;
      float4 mt = pmeta[pglob];
      u32 mask = 0;
      #pragma unroll
      for (int ip=0;ip<4;ip++){
        #pragma unroll
        for (int rr=0;rr<4;rr++){
          const int t = ip*4 + rr;
          float st = a2v[t] + mt.x;
          float ct = cv[t]*mt.y;
          float num0 = st - 2.0f*acc[ip][p][rr];
          float argf = fmaf(num0, ct, 1.0f);
          if (argf < argT[ip]){
            float num = fmaxf(num0, 0.0f);
            float ac = fmaxf(fmaf(num, ct, 1.0f), 1.0000001f);
            float d = __log2f(ac + sqrtf((ac-1.0f)*(ac+1.0f))) * mt.z;  // acosh/ln2*sig
            u32 key = (__float_as_uint(d) & 0xFFFFE000u) | (u32)pglob;
            candw[col*65 + (ip*16 + quad*4 + rr)] = key;
            mask |= 1u << (ip*4 + rr);
          }
        }
      }
      masks[wave][lane] = mask;
      __syncthreads();
      {
        const int tt = lane;                    // token within wave half
        const int mq = ((tt>>2)&3)*16;          // quad-group base lane
        const int sh = ((tt>>4)<<2) | (tt&3);   // mask bit for this token
        u32 worst = lst[15];
        #pragma unroll 4
        for (int c=0;c<16;c++){
          if ((masks[wave][mq+c] >> sh) & 1u){
            u32 v = candw[c*65 + tt];
            if (v < worst){
              u32 tv = v;
              #pragma unroll
              for (int jj=0;jj<16;jj++){
                u32 a = lst[jj];
                u32 mn = tv < a ? tv : a;
                u32 mx = tv < a ? a : tv;
                lst[jj] = mn; tv = mx;
              }
              worst = lst[15];
            }
          }
        }
      }
      __syncthreads();
    }
  }
  {
    u32* dst = plist + ((size_t)(t0 + wm + lane)*NLIST + s*2 + (wave&1))*16;
    #pragma unroll
    for (int j=0;j<16;j++) dst[j] = lst[j];
  }
}

// ---- fused: merge NLIST lists/token (wave-parallel), gather, log0 ----
__global__ __launch_bounds__(256) void gather_log0(
    const u32* __restrict__ plist, const u16* __restrict__ memb, u16* __restrict__ out)
{
  __shared__ u32 keysh[NLIST*16];            // 512 keys
  __shared__ float wsh[KTOP]; __shared__ int ish[KTOP];
  int n = blockIdx.x, tid = threadIdx.x;
  keysh[tid]     = plist[(size_t)n*NLIST*16 + tid];
  keysh[tid+256] = plist[(size_t)n*NLIST*16 + tid + 256];
  __syncthreads();
  if (tid < 64){
    // lane l<NLIST owns sorted list l; 16 rounds of wave-min; keys unique
    int ptr = 0;
    u32 head = (tid < NLIST) ? keysh[tid*16] : 0xFFFFFFFFu;
    for (int j=0;j<KTOP;j++){
      u32 m = head;
      #pragma unroll
      for (int o=32;o;o>>=1){
        u32 v = (u32)__shfl_xor((int)m, o);
        m = v < m ? v : m;
      }
      if (head == m && tid < NLIST){
        ptr++;
        head = (ptr < 16) ? keysh[tid*16 + ptr] : 0xFFFFFFFFu;
      }
      if (tid == 0){
        wsh[j] = exp2f(-__uint_as_float(m & 0xFFFFE000u));   // exp(-d), log2 key
        ish[j] = (int)(m & 0x1FFFu);
      }
    }
  }
  __syncthreads();
  float v[3];
  #pragma unroll
  for (int j=0;j<3;j++){
    int cdx = tid + 256*j;
    float sv = 0.f;
    #pragma unroll
    for (int k=0;k<KTOP;k++) sv += wsh[k]*bf2f(memb[(size_t)ish[k]*HDIM + cdx]);
    v[j] = sv;
  }
  float ss = block_sum(v[0]*v[0]+v[1]*v[1]+v[2]*v[2]);
  float nn = sqrtf(ss);
  float nc = fminf(fmaxf(nn, 1e-5f), 1.0f-1e-5f);
  float sc = atanhf(nc)/nc;
  #pragma unroll
  for (int j=0;j<3;j++) out[(size_t)n*HDIM + tid + 256*j] = f2bf(v[j]*sc);
}

extern "C" void kernel_launch(void* const* d_in, const int* in_sizes, int n_in,
                              void* d_out, int out_size, void* d_ws, size_t ws_size,
                              hipStream_t stream)
{
  const float* x    = (const float*)d_in[0];
  const float* ew1  = (const float*)d_in[1];
  const float* eb1  = (const float*)d_in[2];
  const float* eg   = (const float*)d_in[3];
  const float* ebe  = (const float*)d_in[4];
  const float* ew2  = (const float*)d_in[5];
  const float* eb2  = (const float*)d_in[6];
  const float* dw1  = (const float*)d_in[7];
  const float* db1  = (const float*)d_in[8];
  const float* dg   = (const float*)d_in[9];
  const float* dbe  = (const float*)d_in[10];
  const float* dw2  = (const float*)d_in[11];
  const float* db2  = (const float*)d_in[12];
  const float* mem  = (const float*)d_in[13];
  const float* imp  = (const float*)d_in[14];

  const size_t NE = (size_t)N_TOK*HDIM;       // 6,291,456
  float* out0 = (float*)d_out;                // fp32 output 0
  float* out1 = out0 + NE;                    // fp32 output 1 (pattern)
  u16* patb = (u16*)d_out;                    // bf16 pattern, inside output0 range
  const size_t SWE = (size_t)HDIM*H2DIM;
  u16* w1t  = (u16*)d_out + NE;
  u16* w2t  = w1t + SWE;
  u16* w1td = w1t + 2*SWE;
  u16* w2td = w1t + 3*SWE;                    // ends < output0 end

  char* w = (char*)d_ws;
  size_t off = 0;
  u16* vbuf = (u16*)(w+off); off += NE*2;                    // bf16; also h2 alias
  u16* h1b  = (u16*)(w+off); off += (size_t)N_TOK*H2DIM*2;   // bf16; ln_gelu in-place
  u16* memb = h1b;                                            // alias: live enc-end..gather
  float* a2f = (float*)(w+off); off += (size_t)N_TOK*4;
  float* iva = (float*)(w+off); off += (size_t)N_TOK*4;
  off = (off+15)&~(size_t)15;
  unsigned int* sigminp = (unsigned int*)(w+off); off += 16;
  float4* pmeta = (float4*)(w+off); off += (size_t)PMEM*16;
  u32* plist = (u32*)(w+off); off += (size_t)N_TOK*NLIST*16*4;  // 16.8 MB
  (void)in_sizes; (void)n_in; (void)out_size; (void)ws_size;

  dim3 blk(256);
  transpose_f2b<<<dim3(H2DIM/32, HDIM/32), blk, 0, stream>>>(ew1, w1t,  HDIM,  H2DIM);
  transpose_f2b<<<dim3(HDIM/32, H2DIM/32), blk, 0, stream>>>(ew2, w2t,  H2DIM, HDIM);
  transpose_f2b<<<dim3(H2DIM/32, HDIM/32), blk, 0, stream>>>(dw1, w1td, HDIM,  H2DIM);
  transpose_f2b<<<dim3(HDIM/32, H2DIM/32), blk, 0, stream>>>(dw2, w2td, H2DIM, HDIM);
  // encoder
  log0_rows<<<N_TOK, blk, 0, stream>>>(x, vbuf);
  gemm_bt<<<dim3(H2DIM/128, N_TOK/128), blk, 0, stream>>>(vbuf, w1t, eb1, h1b, N_TOK, H2DIM, HDIM);
  ln_gelu<<<N_TOK, blk, 0, stream>>>(h1b, eg, ebe, h1b);
  gemm_bt<<<dim3(HDIM/128, N_TOK/128), blk, 0, stream>>>(h1b, w2t, eb2, vbuf, N_TOK, HDIM, H2DIM);
  exp0_rows<<<N_TOK, blk, 0, stream>>>(vbuf, out1, patb, a2f, iva);
  // retrieval (memb aliases h1b — dead between encoder and decoder)
  hipMemsetAsync(sigminp, 0x7F, 4, stream);   // FLT_MAX-ish init for atomicMin
  prep_mem<<<PMEM, blk, 0, stream>>>(mem, imp, memb, pmeta, sigminp);
  dist_topk<<<dim3(N_TOK/128, DSPLIT), blk, 0, stream>>>(patb, memb, a2f, iva, pmeta, sigminp, plist);
  gather_log0<<<N_TOK, blk, 0, stream>>>(plist, memb, vbuf);
  // decoder
  gemm_bt<<<dim3(H2DIM/128, N_TOK/128), blk, 0, stream>>>(vbuf, w1td, db1, h1b, N_TOK, H2DIM, HDIM);
  ln_gelu<<<N_TOK, blk, 0, stream>>>(h1b, dg, dbe, h1b);
  gemm_bt<<<dim3(HDIM/128, N_TOK/128), blk, 0, stream>>>(h1b, w2td, db2, vbuf, N_TOK, HDIM, H2DIM);
  exp0_rows<<<N_TOK, blk, 0, stream>>>(vbuf, out0, nullptr, nullptr, nullptr);
}

// Round 14
// 659.134 us; speedup vs baseline: 1.1475x; 1.1475x over previous
//
#include <hip/hip_runtime.h>

// PatternLearner on MI355X (gfx950). Inputs fp32, outputs fp32.
// d_out = [output0 (N*H) | output1=pattern (N*H)] fp32.
// Scratch-in-d_out: patb(bf16) bytes [0,12.58M), w1t..w2td bytes [12.58M,22.02M)
// — inside output0's byte range, overwritten only by the final exp0.
// R13/R14 (R14 = R13 resubmitted after infra fail) = R10 base (best measured,
// 653us: dist_topk v9b 128x128@DSPLIT=16 with padded cand + wave-parallel
// gather merge; gemm_bt R3 stage-ahead dbuf@(256,2)) + two non-dist fixes:
//  (a) gather_log0 vectorized gather: threads 0-95 own bf16x8 chunks, 16
//      coalesced 16B loads (was 48 scalar u16 loads/thread), 16B store.
//  (b) 4 transposes fused into one launch (grid z=0..3).
// R11/R12's single-buffer gemm@(256,3) and transcendental-free filter both
// REVERTED (measured regressions: +93us non-dist, +10us dist).

#define N_TOK 8192
#define HDIM  768
#define H2DIM 1536
#define PMEM  8192
#define KTOP  16
#define DSPLIT 16
#define CHUNK_N 128
#define DCHUNKS (PMEM/DSPLIT/CHUNK_N)   // 4
#define BKD 64
#define KSTEPS (HDIM/BKD)               // 12
#define NLIST (DSPLIT*2)                // 32 sorted lists per token

typedef __attribute__((ext_vector_type(8))) short bf16x8;   // 8 bf16 = 4 VGPRs
typedef __attribute__((ext_vector_type(4))) float f32x4;
typedef unsigned short u16;
typedef unsigned int   u32;

__device__ __forceinline__ float bf2f(u16 u){ return __uint_as_float(((u32)u)<<16); }
__device__ __forceinline__ u16 f2bf(float f){
  u32 x = __float_as_uint(f);
  return (u16)((x + 0x7FFFu + ((x>>16)&1u)) >> 16);   // RNE
}
__device__ __forceinline__ void lds_dma16(const void* g, void* l){
  __builtin_amdgcn_global_load_lds(
      (const __attribute__((address_space(1))) void*)g,
      (__attribute__((address_space(3))) void*)l, 16, 0, 0);
}

__device__ __forceinline__ float block_sum(float s){
  #pragma unroll
  for (int o=32;o;o>>=1) s += __shfl_xor(s,o);
  __shared__ float ps[4];
  int tid = threadIdx.x;
  if ((tid&63)==0) ps[tid>>6] = s;
  __syncthreads();
  return ps[0]+ps[1]+ps[2]+ps[3];
}

// ---- log0: v = atanh(nc)*x/nc. fp32 in, bf16 out ----
__global__ __launch_bounds__(256) void log0_rows(const float* __restrict__ in, u16* __restrict__ out){
  int r = blockIdx.x, tid = threadIdx.x;
  size_t ro = (size_t)r*HDIM;
  float v0=in[ro+tid], v1=in[ro+tid+256], v2=in[ro+tid+512];
  float s = block_sum(v0*v0+v1*v1+v2*v2);
  float n = sqrtf(s);
  float nc = fminf(fmaxf(n, 1e-5f), 1.0f-1e-5f);
  float sc = atanhf(nc)/nc;
  u16* orow = out + ro;
  orow[tid]=f2bf(v0*sc); orow[tid+256]=f2bf(v1*sc); orow[tid+512]=f2bf(v2*sc);
}

// ---- exp0: y = tanh(nm)*x/nm. bf16 in; fp32 out (+optional bf16 copy, a2/iva)
__global__ __launch_bounds__(256) void exp0_rows(const u16* __restrict__ in, float* __restrict__ outf,
                                                 u16* outb, float* a2p, float* ivp){
  int r = blockIdx.x, tid = threadIdx.x;
  const u16* row = in + (size_t)r*HDIM;
  float v0=bf2f(row[tid]), v1=bf2f(row[tid+256]), v2=bf2f(row[tid+512]);
  float s = block_sum(v0*v0+v1*v1+v2*v2);
  float n = sqrtf(s);
  float nm = fmaxf(n, 1e-5f);
  float sc = tanhf(nm)/nm;
  size_t ro = (size_t)r*HDIM;
  outf[ro+tid]=v0*sc; outf[ro+tid+256]=v1*sc; outf[ro+tid+512]=v2*sc;
  if (outb != nullptr){
    outb[ro+tid]=f2bf(v0*sc); outb[ro+tid+256]=f2bf(v1*sc); outb[ro+tid+512]=f2bf(v2*sc);
  }
  if (a2p != nullptr && tid==0){
    float a2 = fminf(sc*sc*s, 1.0f-1e-5f);
    a2p[r] = a2; ivp[r] = 1.0f/(1.0f-a2);
  }
}

// ---- memory prep: memb(bf16), pmeta = {b2, 1/(1-b2), sigmoid(imp), 0} ----
__global__ __launch_bounds__(256) void prep_mem(const float* __restrict__ mem, const float* __restrict__ imp,
                                                u16* __restrict__ memb, float4* __restrict__ pmeta){
  int p = blockIdx.x, tid = threadIdx.x;
  size_t ro = (size_t)p*HDIM;
  float v0=mem[ro+tid], v1=mem[ro+tid+256], v2=mem[ro+tid+512];
  memb[ro+tid]=f2bf(v0); memb[ro+tid+256]=f2bf(v1); memb[ro+tid+512]=f2bf(v2);
  float s = block_sum(v0*v0+v1*v1+v2*v2);
  if (tid==0){
    float b2 = fminf(s, 1.0f-1e-5f);
    float4 m; m.x=b2; m.y=1.0f/(1.0f-b2); m.z=1.0f/(1.0f+__expf(-imp[p])); m.w=0.f;
    pmeta[p]=m;
  }
}

// ---- LayerNorm + exact gelu over rows of 1536; in-place safe ----
__global__ __launch_bounds__(256) void ln_gelu(const u16* __restrict__ in, const float* __restrict__ g,
                                               const float* __restrict__ be, u16* __restrict__ out){
  int r = blockIdx.x, tid = threadIdx.x;
  const u16* row = in + (size_t)r*H2DIM;
  float h[6]; float s=0.f, s2=0.f;
  #pragma unroll
  for (int j=0;j<6;j++){ float v=bf2f(row[tid+256*j]); h[j]=v; s+=v; s2+=v*v; }
  #pragma unroll
  for (int o=32;o;o>>=1){ s += __shfl_xor(s,o); s2 += __shfl_xor(s2,o); }
  __shared__ float ps[4], ps2[4];
  if ((tid&63)==0){ ps[tid>>6]=s; ps2[tid>>6]=s2; }
  __syncthreads();
  s = ps[0]+ps[1]+ps[2]+ps[3]; s2 = ps2[0]+ps2[1]+ps2[2]+ps2[3];
  float mu  = s*(1.0f/H2DIM);
  float var = fmaxf(s2*(1.0f/H2DIM) - mu*mu, 0.0f);
  float rstd = rsqrtf(var + 1e-5f);
  u16* orow = out + (size_t)r*H2DIM;
  #pragma unroll
  for (int j=0;j<6;j++){
    int c = tid+256*j;
    float y = (h[j]-mu)*rstd*g[c] + be[c];
    float ge = 0.5f*y*(1.0f + erff(y*0.70710678118654752f));
    orow[c] = f2bf(ge);
  }
}

// ---- GEMM: C[M,N] = A[M,K]*BT[N,K]^T + bias; bf16 in/out, fp32 acc/bias ----
// m97 structure + stage-ahead double-buffer @(256,2) (R3/R10; proven best).
__global__ __launch_bounds__(256,2) void gemm_bt(
    const u16* __restrict__ A, const u16* __restrict__ B,
    const float* __restrict__ bias, u16* __restrict__ C,
    int M, int Nn, int Kk)
{
  __shared__ u16 As[2][128*64];   // 2 x 16 KB
  __shared__ u16 Bs[2][128*64];   // 2 x 16 KB
  const int tid = threadIdx.x;
  const int m0 = blockIdx.y*128, n0 = blockIdx.x*128;
  const int wave = tid>>6, lane = tid&63;
  const int wm = (wave>>1)*64, wn = (wave&1)*64;
  const int col = lane&15, quad = lane>>4;
  const int nst = Kk>>6;

  int sr[4], sk[4];
  #pragma unroll
  for (int j=0;j<4;j++){
    int c = j*256 + wave*64 + lane;
    int r = c>>3, kc = c&7;
    sr[j] = r; sk[j] = (kc ^ (r&7))*8;
  }

  #pragma unroll
  for (int j=0;j<4;j++){
    lds_dma16(A + (size_t)(m0+sr[j])*Kk + sk[j], &As[0][(j*256 + wave*64)*8]);
    lds_dma16(B + (size_t)(n0+sr[j])*Kk + sk[j], &Bs[0][(j*256 + wave*64)*8]);
  }
  __syncthreads();

  f32x4 acc[4][4] = {};
  for (int t=0; t<nst; t++){
    if (t+1 < nst){
      const int k0n = (t+1)<<6;
      const int bn = (t+1)&1;
      #pragma unroll
      for (int j=0;j<4;j++){
        lds_dma16(A + (size_t)(m0+sr[j])*Kk + k0n + sk[j], &As[bn][(j*256 + wave*64)*8]);
        lds_dma16(B + (size_t)(n0+sr[j])*Kk + k0n + sk[j], &Bs[bn][(j*256 + wave*64)*8]);
      }
    }
    const u16* Ac = &As[t&1][0];
    const u16* Bc = &Bs[t&1][0];
    #pragma unroll
    for (int kk=0;kk<2;kk++){
      const int kq = kk*4 + quad;
      bf16x8 af[4], bfr[4];
      #pragma unroll
      for (int i=0;i<4;i++){
        int ar = wm + i*16 + col;
        af[i]  = *(const bf16x8*)&Ac[ar*64 + ((kq ^ (ar&7))*8)];
      }
      #pragma unroll
      for (int j=0;j<4;j++){
        int br = wn + j*16 + col;
        bfr[j] = *(const bf16x8*)&Bc[br*64 + ((kq ^ (br&7))*8)];
      }
      #pragma unroll
      for (int i=0;i<4;i++)
        #pragma unroll
        for (int j=0;j<4;j++)
          acc[i][j] = __builtin_amdgcn_mfma_f32_16x16x32_bf16(af[i], bfr[j], acc[i][j], 0,0,0);
    }
    __syncthreads();
  }
  #pragma unroll
  for (int j=0;j<4;j++){
    int cc = n0 + wn + j*16 + col;
    float bv = bias[cc];
    #pragma unroll
    for (int i=0;i<4;i++){
      int rbase = m0 + wm + i*16 + quad*4;
      #pragma unroll
      for (int rr=0;rr<4;rr++)
        C[(size_t)(rbase+rr)*Nn + cc] = f2bf(acc[i][j][rr] + bv);
    }
  }
}

// ---- fused 4x transpose fp32 -> bf16 (z = which matrix) ----
// z even: R=HDIM,C=H2DIM (w1/w1d); z odd: R=H2DIM,C=HDIM (w2/w2d, grid xy swapped)
__global__ __launch_bounds__(256) void transpose4_f2b(
    const float* __restrict__ s0, u16* __restrict__ d0,
    const float* __restrict__ s1, u16* __restrict__ d1,
    const float* __restrict__ s2, u16* __restrict__ d2,
    const float* __restrict__ s3, u16* __restrict__ d3)
{
  __shared__ float tile[32][33];
  const int z = blockIdx.z;
  const float* in; u16* outp; int R, Ccols, bx, by;
  if (z==0){ in=s0; outp=d0; R=HDIM;  Ccols=H2DIM; bx=blockIdx.x; by=blockIdx.y; }
  else if (z==1){ in=s1; outp=d1; R=H2DIM; Ccols=HDIM; bx=blockIdx.y; by=blockIdx.x; }
  else if (z==2){ in=s2; outp=d2; R=HDIM;  Ccols=H2DIM; bx=blockIdx.x; by=blockIdx.y; }
  else { in=s3; outp=d3; R=H2DIM; Ccols=HDIM; bx=blockIdx.y; by=blockIdx.x; }
  int tx = threadIdx.x & 31, ty = threadIdx.x >> 5;
  int c0 = bx*32, r0 = by*32;
  #pragma unroll
  for (int i=0;i<32;i+=8) tile[ty+i][tx] = in[(size_t)(r0+ty+i)*Ccols + c0+tx];
  __syncthreads();
  #pragma unroll
  for (int i=0;i<32;i+=8) outp[(size_t)(c0+ty+i)*R + r0+tx] = f2bf(tile[tx][ty+i]);
}

// ---- dist_topk v9b: 128x128 tile @ DSPLIT=16, 64-lane merge, padded cand ----
// grid (N_TOK/128, DSPLIT) = (64,16) = 1024 blocks. Block: 128 tokens; wave
// (wm=(w>>1)*64 token-half, wn=(w&1)*64 pattern-half) owns 64x64. K staged in
// steps of 64 via global_load_lds + XOR chunk swizzle (as gemm_bt). Lane tt
// (all 64) keeps token (wm+tt)'s top-16 of this wave's pattern-half in regs.
// Selection: 4 passes of 16 patterns; cand[wave][col][tt] (pitch 65 -> bank
// (col+quad*4)&31, <=2-way) unions dead A-tile; single-bit masks; log2 keys;
// log2 lower-bound filter. packed key = (log2dist_bits & ~0x1FFF) | pattern_idx.
__global__ __launch_bounds__(256,3) void dist_topk(
    const u16* __restrict__ patb, const u16* __restrict__ memb,
    const float* __restrict__ a2f, const float* __restrict__ iva,
    const float4* __restrict__ pmeta, u32* __restrict__ plist)
{
  __shared__ char usm[16640 + 16384];    // union{Atile 16K, cand 16.64K} + Btile 16K
  u16* Atile = (u16*)usm;                // 128 x 64, swizzled
  u16* Btile = (u16*)(usm + 16640);      // 128 x 64, swizzled
  u32* candb = (u32*)usm;                // cand[wave][col][tt] pitch 65
  __shared__ u32 masks[4][64];
  __shared__ float a2s[128], iv2[128];
  const int tid = threadIdx.x;
  const int wave = tid>>6, lane = tid&63;
  const int col = lane&15, quad = lane>>4;
  const int wm = (wave>>1)*64, wn = (wave&1)*64;
  const int t0 = blockIdx.x*128;
  const int s  = blockIdx.y;
  const int pb0 = s*(PMEM/DSPLIT);       // 512-pattern slice
  if (tid < 128){ a2s[tid] = a2f[t0+tid]; iv2[tid] = 2.0f*iva[t0+tid]; }
  u32 lst[16];
  #pragma unroll
  for (int j=0;j<16;j++) lst[j] = 0xFFFFFFFFu;
  // staging coords (A and B share the formula: 128x64 tiles)
  int sr[4], sk[4];
  #pragma unroll
  for (int j=0;j<4;j++){
    int c = j*256 + wave*64 + lane;
    int r = c>>3, kc = c&7;
    sr[j] = r; sk[j] = (kc ^ (r&7))*8;
  }
  u32* candw = candb + wave*(16*65);
  __syncthreads();

  for (int nc=0; nc<DCHUNKS; nc++){
    const int pbase = pb0 + nc*CHUNK_N;
    f32x4 acc[4][4] = {};
    for (int ks=0; ks<KSTEPS; ks++){
      const int k0 = ks*BKD;
      __syncthreads();                      // tiles free (prev MFMA / selection done)
      #pragma unroll
      for (int j=0;j<4;j++){
        lds_dma16(patb + (size_t)(t0+sr[j])*HDIM + k0 + sk[j], Atile + (size_t)(j*256 + wave*64)*8);
        lds_dma16(memb + (size_t)(pbase+sr[j])*HDIM + k0 + sk[j], Btile + (size_t)(j*256 + wave*64)*8);
      }
      __syncthreads();                      // vmcnt(0) drained before barrier
      #pragma unroll
      for (int kk=0;kk<2;kk++){
        const int kq = kk*4 + quad;
        bf16x8 af[4], bfr[4];
        #pragma unroll
        for (int i=0;i<4;i++){
          int ar = wm + i*16 + col;
          af[i] = *(const bf16x8*)&Atile[ar*64 + ((kq ^ (ar&7))*8)];
        }
        #pragma unroll
        for (int j=0;j<4;j++){
          int br = wn + j*16 + col;
          bfr[j] = *(const bf16x8*)&Btile[br*64 + ((kq ^ (br&7))*8)];
        }
        #pragma unroll
        for (int i=0;i<4;i++)
          #pragma unroll
          for (int j=0;j<4;j++)
            acc[i][j] = __builtin_amdgcn_mfma_f32_16x16x32_bf16(af[i], bfr[j], acc[i][j], 0,0,0);
      }
    }
    __syncthreads();   // all tile reads done before cand (union) is written
    // selection: 4 passes of 16 patterns (p = acc's j index)
    #pragma unroll
    for (int p=0;p<4;p++){
      u32 thrU[4][4];
      #pragma unroll
      for (int ip=0;ip<4;ip++)
        #pragma unroll
        for (int rr=0;rr<4;rr++)
          thrU[ip][rr] = (u32)__shfl((int)lst[15], ip*16 + quad*4 + rr);
      const int pglob = pbase + wn + p*16 + col;
      float4 mt = pmeta[pglob];
      u32 mask = 0;
      #pragma unroll
      for (int ip=0;ip<4;ip++){
        #pragma unroll
        for (int rr=0;rr<4;rr++){
          const int tt = ip*16 + quad*4 + rr;
          float num = fmaxf(a2s[wm+tt] + mt.x - 2.0f*acc[ip][p][rr], 0.0f);
          float arg = fmaf(num, iv2[wm+tt]*mt.y, 1.0f);
          arg = fmaxf(arg, 1.0000001f);
          // lower bound: log2(dist) >= log2(arg)*sig -> safe reject
          float lb = __log2f(arg) * mt.z;
          u32 lbT = __float_as_uint(lb) & 0xFFFFE000u;
          if (lbT < thrU[ip][rr]){
            float d = __log2f(arg + sqrtf((arg-1.0f)*(arg+1.0f))) * mt.z;  // acosh/ln2*sig
            u32 key = (__float_as_uint(d) & 0xFFFFE000u) | (u32)pglob;
            if (key < thrU[ip][rr]){
              candw[col*65 + tt] = key;
              mask |= 1u << (ip*4 + rr);
            }
          }
        }
      }
      masks[wave][lane] = mask;
      __syncthreads();
      {
        const int tt = lane;                    // token within wave half
        const int mq = ((tt>>2)&3)*16;          // quad-group base lane
        const int sh = ((tt>>4)<<2) | (tt&3);   // mask bit for this token
        u32 worst = lst[15];
        #pragma unroll 4
        for (int c=0;c<16;c++){
          if ((masks[wave][mq+c] >> sh) & 1u){
            u32 v = candw[c*65 + tt];
            if (v < worst){
              u32 tv = v;
              #pragma unroll
              for (int jj=0;jj<16;jj++){
                u32 a = lst[jj];
                u32 mn = tv < a ? tv : a;
                u32 mx = tv < a ? a : tv;
                lst[jj] = mn; tv = mx;
              }
              worst = lst[15];
            }
          }
        }
      }
      __syncthreads();
    }
  }
  {
    u32* dst = plist + ((size_t)(t0 + wm + lane)*NLIST + s*2 + (wave&1))*16;
    #pragma unroll
    for (int j=0;j<16;j++) dst[j] = lst[j];
  }
}

// ---- fused: merge NLIST lists/token (wave-parallel), vectorized gather, log0 ----
__global__ __launch_bounds__(256) void gather_log0(
    const u32* __restrict__ plist, const u16* __restrict__ memb, u16* __restrict__ out)
{
  __shared__ u32 keysh[NLIST*16];            // 512 keys
  __shared__ float wsh[KTOP]; __shared__ int ish[KTOP];
  int n = blockIdx.x, tid = threadIdx.x;
  keysh[tid]     = plist[(size_t)n*NLIST*16 + tid];
  keysh[tid+256] = plist[(size_t)n*NLIST*16 + tid + 256];
  __syncthreads();
  if (tid < 64){
    // lane l<NLIST owns sorted list l; 16 rounds of wave-min; keys unique
    int ptr = 0;
    u32 head = (tid < NLIST) ? keysh[tid*16] : 0xFFFFFFFFu;
    for (int j=0;j<KTOP;j++){
      u32 m = head;
      #pragma unroll
      for (int o=32;o;o>>=1){
        u32 v = (u32)__shfl_xor((int)m, o);
        m = v < m ? v : m;
      }
      if (head == m && tid < NLIST){
        ptr++;
        head = (ptr < 16) ? keysh[tid*16 + ptr] : 0xFFFFFFFFu;
      }
      if (tid == 0){
        wsh[j] = exp2f(-__uint_as_float(m & 0xFFFFE000u));   // exp(-d), log2 key
        ish[j] = (int)(m & 0x1FFFu);
      }
    }
  }
  __syncthreads();
  // vectorized gather: thread t<96 owns elems [t*8, t*8+8) of the 768-row
  float v[8] = {};
  if (tid < 96){
    #pragma unroll
    for (int k=0;k<KTOP;k++){
      bf16x8 rv = *(const bf16x8*)(memb + (size_t)ish[k]*HDIM + tid*8);
      float wk = wsh[k];
      #pragma unroll
      for (int j=0;j<8;j++) v[j] = fmaf(wk, bf2f((u16)rv[j]), v[j]);
    }
  }
  float ssl = 0.f;
  #pragma unroll
  for (int j=0;j<8;j++) ssl += v[j]*v[j];
  float ss = block_sum(ssl);           // threads >=96 contribute 0
  float nn = sqrtf(ss);
  float nc = fminf(fmaxf(nn, 1e-5f), 1.0f-1e-5f);
  float sc = atanhf(nc)/nc;
  if (tid < 96){
    u16 ov[8];
    #pragma unroll
    for (int j=0;j<8;j++) ov[j] = f2bf(v[j]*sc);
    *(bf16x8*)(out + (size_t)n*HDIM + tid*8) = *(const bf16x8*)ov;
  }
}

extern "C" void kernel_launch(void* const* d_in, const int* in_sizes, int n_in,
                              void* d_out, int out_size, void* d_ws, size_t ws_size,
                              hipStream_t stream)
{
  const float* x    = (const float*)d_in[0];
  const float* ew1  = (const float*)d_in[1];
  const float* eb1  = (const float*)d_in[2];
  const float* eg   = (const float*)d_in[3];
  const float* ebe  = (const float*)d_in[4];
  const float* ew2  = (const float*)d_in[5];
  const float* eb2  = (const float*)d_in[6];
  const float* dw1  = (const float*)d_in[7];
  const float* db1  = (const float*)d_in[8];
  const float* dg   = (const float*)d_in[9];
  const float* dbe  = (const float*)d_in[10];
  const float* dw2  = (const float*)d_in[11];
  const float* db2  = (const float*)d_in[12];
  const float* mem  = (const float*)d_in[13];
  const float* imp  = (const float*)d_in[14];

  const size_t NE = (size_t)N_TOK*HDIM;       // 6,291,456
  float* out0 = (float*)d_out;                // fp32 output 0
  float* out1 = out0 + NE;                    // fp32 output 1 (pattern)
  u16* patb = (u16*)d_out;                    // bf16 pattern, inside output0 range
  const size_t SWE = (size_t)HDIM*H2DIM;
  u16* w1t  = (u16*)d_out + NE;
  u16* w2t  = w1t + SWE;
  u16* w1td = w1t + 2*SWE;
  u16* w2td = w1t + 3*SWE;                    // ends < output0 end

  char* w = (char*)d_ws;
  size_t off = 0;
  u16* vbuf = (u16*)(w+off); off += NE*2;                    // bf16; also h2 alias
  u16* h1b  = (u16*)(w+off); off += (size_t)N_TOK*H2DIM*2;   // bf16; ln_gelu in-place
  u16* memb = h1b;                                            // alias: live enc-end..gather
  float* a2f = (float*)(w+off); off += (size_t)N_TOK*4;
  float* iva = (float*)(w+off); off += (size_t)N_TOK*4;
  off = (off+15)&~(size_t)15;
  float4* pmeta = (float4*)(w+off); off += (size_t)PMEM*16;
  u32* plist = (u32*)(w+off); off += (size_t)N_TOK*NLIST*16*4;  // 16.8 MB
  (void)in_sizes; (void)n_in; (void)out_size; (void)ws_size;

  dim3 blk(256);
  transpose4_f2b<<<dim3(H2DIM/32, HDIM/32, 4), blk, 0, stream>>>(
      ew1, w1t, ew2, w2t, dw1, w1td, dw2, w2td);
  // encoder
  log0_rows<<<N_TOK, blk, 0, stream>>>(x, vbuf);
  gemm_bt<<<dim3(H2DIM/128, N_TOK/128), blk, 0, stream>>>(vbuf, w1t, eb1, h1b, N_TOK, H2DIM, HDIM);
  ln_gelu<<<N_TOK, blk, 0, stream>>>(h1b, eg, ebe, h1b);
  gemm_bt<<<dim3(HDIM/128, N_TOK/128), blk, 0, stream>>>(h1b, w2t, eb2, vbuf, N_TOK, HDIM, H2DIM);
  exp0_rows<<<N_TOK, blk, 0, stream>>>(vbuf, out1, patb, a2f, iva);
  // retrieval (memb aliases h1b — dead between encoder and decoder)
  prep_mem<<<PMEM, blk, 0, stream>>>(mem, imp, memb, pmeta);
  dist_topk<<<dim3(N_TOK/128, DSPLIT), blk, 0, stream>>>(patb, memb, a2f, iva, pmeta, plist);
  gather_log0<<<N_TOK, blk, 0, stream>>>(plist, memb, vbuf);
  // decoder
  gemm_bt<<<dim3(H2DIM/128, N_TOK/128), blk, 0, stream>>>(vbuf, w1td, db1, h1b, N_TOK, H2DIM, HDIM);
  ln_gelu<<<N_TOK, blk, 0, stream>>>(h1b, dg, dbe, h1b);
  gemm_bt<<<dim3(HDIM/128, N_TOK/128), blk, 0, stream>>>(h1b, w2td, db2, vbuf, N_TOK, HDIM, H2DIM);
  exp0_rows<<<N_TOK, blk, 0, stream>>>(vbuf, out0, nullptr, nullptr, nullptr);
}

// Round 16
// 629.823 us; speedup vs baseline: 1.2009x; 1.0465x over previous
//
#include <hip/hip_runtime.h>

// PatternLearner on MI355X (gfx950). Inputs fp32, outputs fp32.
// d_out = [output0 (N*H) | output1=pattern (N*H)] fp32.
// Scratch-in-d_out: patb(bf16) bytes [0,12.58M), w1t..w2td bytes [12.58M,22.02M)
// — inside output0's byte range, overwritten only by the final exp0.
// R15/R16 (R16 = R15 resubmitted after infra fail): dist_topk v11 = v9b with
// (a) selection 4->2 passes (u32 mask of 32 pattern-cols; cand [32][65]/wave
// unions BOTH dead tiles; halves selection barriers + thrU refreshes),
// (b) cross-wave pair merge (waves sharing tokens merge sorted-16s in-kernel
// -> NLIST=16, plist halves to 8.4MB).
// gemm_bt stays R3 stage-ahead dbuf@(256,2) (best measured).
// gather keeps wave-parallel merge + vectorized gather.

#define N_TOK 8192
#define HDIM  768
#define H2DIM 1536
#define PMEM  8192
#define KTOP  16
#define DSPLIT 16
#define CHUNK_N 128
#define DCHUNKS (PMEM/DSPLIT/CHUNK_N)   // 4
#define BKD 64
#define KSTEPS (HDIM/BKD)               // 12
#define NLIST DSPLIT                    // 16 sorted lists per token (pair-merged)

typedef __attribute__((ext_vector_type(8))) short bf16x8;   // 8 bf16 = 4 VGPRs
typedef __attribute__((ext_vector_type(4))) float f32x4;
typedef unsigned short u16;
typedef unsigned int   u32;

__device__ __forceinline__ float bf2f(u16 u){ return __uint_as_float(((u32)u)<<16); }
__device__ __forceinline__ u16 f2bf(float f){
  u32 x = __float_as_uint(f);
  return (u16)((x + 0x7FFFu + ((x>>16)&1u)) >> 16);   // RNE
}
__device__ __forceinline__ void lds_dma16(const void* g, void* l){
  __builtin_amdgcn_global_load_lds(
      (const __attribute__((address_space(1))) void*)g,
      (__attribute__((address_space(3))) void*)l, 16, 0, 0);
}

__device__ __forceinline__ float block_sum(float s){
  #pragma unroll
  for (int o=32;o;o>>=1) s += __shfl_xor(s,o);
  __shared__ float ps[4];
  int tid = threadIdx.x;
  if ((tid&63)==0) ps[tid>>6] = s;
  __syncthreads();
  return ps[0]+ps[1]+ps[2]+ps[3];
}

// ---- log0: v = atanh(nc)*x/nc. fp32 in, bf16 out ----
__global__ __launch_bounds__(256) void log0_rows(const float* __restrict__ in, u16* __restrict__ out){
  int r = blockIdx.x, tid = threadIdx.x;
  size_t ro = (size_t)r*HDIM;
  float v0=in[ro+tid], v1=in[ro+tid+256], v2=in[ro+tid+512];
  float s = block_sum(v0*v0+v1*v1+v2*v2);
  float n = sqrtf(s);
  float nc = fminf(fmaxf(n, 1e-5f), 1.0f-1e-5f);
  float sc = atanhf(nc)/nc;
  u16* orow = out + ro;
  orow[tid]=f2bf(v0*sc); orow[tid+256]=f2bf(v1*sc); orow[tid+512]=f2bf(v2*sc);
}

// ---- exp0: y = tanh(nm)*x/nm. bf16 in; fp32 out (+optional bf16 copy, a2/iva)
__global__ __launch_bounds__(256) void exp0_rows(const u16* __restrict__ in, float* __restrict__ outf,
                                                 u16* outb, float* a2p, float* ivp){
  int r = blockIdx.x, tid = threadIdx.x;
  const u16* row = in + (size_t)r*HDIM;
  float v0=bf2f(row[tid]), v1=bf2f(row[tid+256]), v2=bf2f(row[tid+512]);
  float s = block_sum(v0*v0+v1*v1+v2*v2);
  float n = sqrtf(s);
  float nm = fmaxf(n, 1e-5f);
  float sc = tanhf(nm)/nm;
  size_t ro = (size_t)r*HDIM;
  outf[ro+tid]=v0*sc; outf[ro+tid+256]=v1*sc; outf[ro+tid+512]=v2*sc;
  if (outb != nullptr){
    outb[ro+tid]=f2bf(v0*sc); outb[ro+tid+256]=f2bf(v1*sc); outb[ro+tid+512]=f2bf(v2*sc);
  }
  if (a2p != nullptr && tid==0){
    float a2 = fminf(sc*sc*s, 1.0f-1e-5f);
    a2p[r] = a2; ivp[r] = 1.0f/(1.0f-a2);
  }
}

// ---- memory prep: memb(bf16), pmeta = {b2, 1/(1-b2), sigmoid(imp), 0} ----
__global__ __launch_bounds__(256) void prep_mem(const float* __restrict__ mem, const float* __restrict__ imp,
                                                u16* __restrict__ memb, float4* __restrict__ pmeta){
  int p = blockIdx.x, tid = threadIdx.x;
  size_t ro = (size_t)p*HDIM;
  float v0=mem[ro+tid], v1=mem[ro+tid+256], v2=mem[ro+tid+512];
  memb[ro+tid]=f2bf(v0); memb[ro+tid+256]=f2bf(v1); memb[ro+tid+512]=f2bf(v2);
  float s = block_sum(v0*v0+v1*v1+v2*v2);
  if (tid==0){
    float b2 = fminf(s, 1.0f-1e-5f);
    float4 m; m.x=b2; m.y=1.0f/(1.0f-b2); m.z=1.0f/(1.0f+__expf(-imp[p])); m.w=0.f;
    pmeta[p]=m;
  }
}

// ---- LayerNorm + exact gelu over rows of 1536; in-place safe ----
__global__ __launch_bounds__(256) void ln_gelu(const u16* __restrict__ in, const float* __restrict__ g,
                                               const float* __restrict__ be, u16* __restrict__ out){
  int r = blockIdx.x, tid = threadIdx.x;
  const u16* row = in + (size_t)r*H2DIM;
  float h[6]; float s=0.f, s2=0.f;
  #pragma unroll
  for (int j=0;j<6;j++){ float v=bf2f(row[tid+256*j]); h[j]=v; s+=v; s2+=v*v; }
  #pragma unroll
  for (int o=32;o;o>>=1){ s += __shfl_xor(s,o); s2 += __shfl_xor(s2,o); }
  __shared__ float ps[4], ps2[4];
  if ((tid&63)==0){ ps[tid>>6]=s; ps2[tid>>6]=s2; }
  __syncthreads();
  s = ps[0]+ps[1]+ps[2]+ps[3]; s2 = ps2[0]+ps2[1]+ps2[2]+ps2[3];
  float mu  = s*(1.0f/H2DIM);
  float var = fmaxf(s2*(1.0f/H2DIM) - mu*mu, 0.0f);
  float rstd = rsqrtf(var + 1e-5f);
  u16* orow = out + (size_t)r*H2DIM;
  #pragma unroll
  for (int j=0;j<6;j++){
    int c = tid+256*j;
    float y = (h[j]-mu)*rstd*g[c] + be[c];
    float ge = 0.5f*y*(1.0f + erff(y*0.70710678118654752f));
    orow[c] = f2bf(ge);
  }
}

// ---- GEMM: C[M,N] = A[M,K]*BT[N,K]^T + bias; bf16 in/out, fp32 acc/bias ----
// m97 structure + stage-ahead double-buffer @(256,2) (R3/R10; proven best).
__global__ __launch_bounds__(256,2) void gemm_bt(
    const u16* __restrict__ A, const u16* __restrict__ B,
    const float* __restrict__ bias, u16* __restrict__ C,
    int M, int Nn, int Kk)
{
  __shared__ u16 As[2][128*64];   // 2 x 16 KB
  __shared__ u16 Bs[2][128*64];   // 2 x 16 KB
  const int tid = threadIdx.x;
  const int m0 = blockIdx.y*128, n0 = blockIdx.x*128;
  const int wave = tid>>6, lane = tid&63;
  const int wm = (wave>>1)*64, wn = (wave&1)*64;
  const int col = lane&15, quad = lane>>4;
  const int nst = Kk>>6;

  int sr[4], sk[4];
  #pragma unroll
  for (int j=0;j<4;j++){
    int c = j*256 + wave*64 + lane;
    int r = c>>3, kc = c&7;
    sr[j] = r; sk[j] = (kc ^ (r&7))*8;
  }

  #pragma unroll
  for (int j=0;j<4;j++){
    lds_dma16(A + (size_t)(m0+sr[j])*Kk + sk[j], &As[0][(j*256 + wave*64)*8]);
    lds_dma16(B + (size_t)(n0+sr[j])*Kk + sk[j], &Bs[0][(j*256 + wave*64)*8]);
  }
  __syncthreads();

  f32x4 acc[4][4] = {};
  for (int t=0; t<nst; t++){
    if (t+1 < nst){
      const int k0n = (t+1)<<6;
      const int bn = (t+1)&1;
      #pragma unroll
      for (int j=0;j<4;j++){
        lds_dma16(A + (size_t)(m0+sr[j])*Kk + k0n + sk[j], &As[bn][(j*256 + wave*64)*8]);
        lds_dma16(B + (size_t)(n0+sr[j])*Kk + k0n + sk[j], &Bs[bn][(j*256 + wave*64)*8]);
      }
    }
    const u16* Ac = &As[t&1][0];
    const u16* Bc = &Bs[t&1][0];
    #pragma unroll
    for (int kk=0;kk<2;kk++){
      const int kq = kk*4 + quad;
      bf16x8 af[4], bfr[4];
      #pragma unroll
      for (int i=0;i<4;i++){
        int ar = wm + i*16 + col;
        af[i]  = *(const bf16x8*)&Ac[ar*64 + ((kq ^ (ar&7))*8)];
      }
      #pragma unroll
      for (int j=0;j<4;j++){
        int br = wn + j*16 + col;
        bfr[j] = *(const bf16x8*)&Bc[br*64 + ((kq ^ (br&7))*8)];
      }
      #pragma unroll
      for (int i=0;i<4;i++)
        #pragma unroll
        for (int j=0;j<4;j++)
          acc[i][j] = __builtin_amdgcn_mfma_f32_16x16x32_bf16(af[i], bfr[j], acc[i][j], 0,0,0);
    }
    __syncthreads();
  }
  #pragma unroll
  for (int j=0;j<4;j++){
    int cc = n0 + wn + j*16 + col;
    float bv = bias[cc];
    #pragma unroll
    for (int i=0;i<4;i++){
      int rbase = m0 + wm + i*16 + quad*4;
      #pragma unroll
      for (int rr=0;rr<4;rr++)
        C[(size_t)(rbase+rr)*Nn + cc] = f2bf(acc[i][j][rr] + bv);
    }
  }
}

// ---- fused 4x transpose fp32 -> bf16 (z = which matrix) ----
__global__ __launch_bounds__(256) void transpose4_f2b(
    const float* __restrict__ s0, u16* __restrict__ d0,
    const float* __restrict__ s1, u16* __restrict__ d1,
    const float* __restrict__ s2, u16* __restrict__ d2,
    const float* __restrict__ s3, u16* __restrict__ d3)
{
  __shared__ float tile[32][33];
  const int z = blockIdx.z;
  const float* in; u16* outp; int R, Ccols, bx, by;
  if (z==0){ in=s0; outp=d0; R=HDIM;  Ccols=H2DIM; bx=blockIdx.x; by=blockIdx.y; }
  else if (z==1){ in=s1; outp=d1; R=H2DIM; Ccols=HDIM; bx=blockIdx.y; by=blockIdx.x; }
  else if (z==2){ in=s2; outp=d2; R=HDIM;  Ccols=H2DIM; bx=blockIdx.x; by=blockIdx.y; }
  else { in=s3; outp=d3; R=H2DIM; Ccols=HDIM; bx=blockIdx.y; by=blockIdx.x; }
  int tx = threadIdx.x & 31, ty = threadIdx.x >> 5;
  int c0 = bx*32, r0 = by*32;
  #pragma unroll
  for (int i=0;i<32;i+=8) tile[ty+i][tx] = in[(size_t)(r0+ty+i)*Ccols + c0+tx];
  __syncthreads();
  #pragma unroll
  for (int i=0;i<32;i+=8) outp[(size_t)(c0+ty+i)*R + r0+tx] = f2bf(tile[tx][ty+i]);
}

// ---- dist_topk v11: 128x128 @ DSPLIT=16; 2-pass selection; pair-merged ----
// grid (N_TOK/128, DSPLIT) = (64,16). Wave (wm,wn) owns 64 tok x 64 pat.
// Selection: 2 passes of 32 patterns (mask bit = j4*16 + ip*4 + rr);
// cand[wave][j4*16+col][tt] pitch 65 (bank = (j4*16+col)+tt mod 32, <=2-way)
// unions BOTH dead tiles. After all chunks: waves (2k,2k+1) share tokens ->
// pair-merge sorted-16s in LDS -> one list/token/slice (NLIST=16).
// packed key = (log2dist_bits & ~0x1FFF) | pattern_idx.
__global__ __launch_bounds__(256,3) void dist_topk(
    const u16* __restrict__ patb, const u16* __restrict__ memb,
    const float* __restrict__ a2f, const float* __restrict__ iva,
    const float4* __restrict__ pmeta, u32* __restrict__ plist)
{
  __shared__ char usm[33280];            // union{Atile16K+Btile16K, cand 33.3K, pairm 8K}
  u16* Atile = (u16*)usm;                // 128 x 64, swizzled
  u16* Btile = (u16*)(usm + 16384);      // 128 x 64, swizzled
  u32* candb = (u32*)usm;                // cand[wave][32][65]
  __shared__ u32 masks[4][64];
  __shared__ float a2s[128], iv2[128];
  const int tid = threadIdx.x;
  const int wave = tid>>6, lane = tid&63;
  const int col = lane&15, quad = lane>>4;
  const int wm = (wave>>1)*64, wn = (wave&1)*64;
  const int t0 = blockIdx.x*128;
  const int s  = blockIdx.y;
  const int pb0 = s*(PMEM/DSPLIT);       // 512-pattern slice
  if (tid < 128){ a2s[tid] = a2f[t0+tid]; iv2[tid] = 2.0f*iva[t0+tid]; }
  u32 lst[16];
  #pragma unroll
  for (int j=0;j<16;j++) lst[j] = 0xFFFFFFFFu;
  // staging coords (A and B share the formula: 128x64 tiles)
  int sr[4], sk[4];
  #pragma unroll
  for (int j=0;j<4;j++){
    int c = j*256 + wave*64 + lane;
    int r = c>>3, kc = c&7;
    sr[j] = r; sk[j] = (kc ^ (r&7))*8;
  }
  u32* candw = candb + wave*(32*65);
  __syncthreads();

  for (int nc=0; nc<DCHUNKS; nc++){
    const int pbase = pb0 + nc*CHUNK_N;
    f32x4 acc[4][4] = {};
    for (int ks=0; ks<KSTEPS; ks++){
      const int k0 = ks*BKD;
      __syncthreads();                      // tiles free (prev MFMA / selection done)
      #pragma unroll
      for (int j=0;j<4;j++){
        lds_dma16(patb + (size_t)(t0+sr[j])*HDIM + k0 + sk[j], Atile + (size_t)(j*256 + wave*64)*8);
        lds_dma16(memb + (size_t)(pbase+sr[j])*HDIM + k0 + sk[j], Btile + (size_t)(j*256 + wave*64)*8);
      }
      __syncthreads();                      // vmcnt(0) drained before barrier
      #pragma unroll
      for (int kk=0;kk<2;kk++){
        const int kq = kk*4 + quad;
        bf16x8 af[4], bfr[4];
        #pragma unroll
        for (int i=0;i<4;i++){
          int ar = wm + i*16 + col;
          af[i] = *(const bf16x8*)&Atile[ar*64 + ((kq ^ (ar&7))*8)];
        }
        #pragma unroll
        for (int j=0;j<4;j++){
          int br = wn + j*16 + col;
          bfr[j] = *(const bf16x8*)&Btile[br*64 + ((kq ^ (br&7))*8)];
        }
        #pragma unroll
        for (int i=0;i<4;i++)
          #pragma unroll
          for (int j=0;j<4;j++)
            acc[i][j] = __builtin_amdgcn_mfma_f32_16x16x32_bf16(af[i], bfr[j], acc[i][j], 0,0,0);
      }
    }
    __syncthreads();   // all tile reads done before cand (union) is written
    // selection: 2 passes of 32 patterns (j = p*2 + j4)
    #pragma unroll
    for (int p=0;p<2;p++){
      u32 thrU[4][4];
      #pragma unroll
      for (int ip=0;ip<4;ip++)
        #pragma unroll
        for (int rr=0;rr<4;rr++)
          thrU[ip][rr] = (u32)__shfl((int)lst[15], ip*16 + quad*4 + rr);
      u32 mask = 0;
      #pragma unroll
      for (int j4=0;j4<2;j4++){
        const int j = p*2 + j4;
        const int pglob = pbase + wn + j*16 + col;
        float4 mt = pmeta[pglob];
        #pragma unroll
        for (int ip=0;ip<4;ip++){
          #pragma unroll
          for (int rr=0;rr<4;rr++){
            const int tt = ip*16 + quad*4 + rr;
            float num = fmaxf(a2s[wm+tt] + mt.x - 2.0f*acc[ip][j][rr], 0.0f);
            float arg = fmaf(num, iv2[wm+tt]*mt.y, 1.0f);
            arg = fmaxf(arg, 1.0000001f);
            // lower bound: log2(dist) >= log2(arg)*sig -> safe reject
            float lb = __log2f(arg) * mt.z;
            u32 lbT = __float_as_uint(lb) & 0xFFFFE000u;
            if (lbT < thrU[ip][rr]){
              float d = __log2f(arg + sqrtf((arg-1.0f)*(arg+1.0f))) * mt.z;  // acosh/ln2*sig
              u32 key = (__float_as_uint(d) & 0xFFFFE000u) | (u32)pglob;
              if (key < thrU[ip][rr]){
                candw[(j4*16 + col)*65 + tt] = key;
                mask |= 1u << (j4*16 + ip*4 + rr);
              }
            }
          }
        }
      }
      masks[wave][lane] = mask;
      __syncthreads();
      {
        const int tt = lane;                    // token within wave half
        const int mq = ((tt>>2)&3)*16;          // quad-group base lane
        const int sh = ((tt>>4)<<2) | (tt&3);   // mask bit (ip*4+rr) for this token
        u32 worst = lst[15];
        #pragma unroll 4
        for (int c=0;c<16;c++){
          u32 m = masks[wave][mq+c];
          #pragma unroll
          for (int j4=0;j4<2;j4++){
            if ((m >> (j4*16 + sh)) & 1u){
              u32 v = candw[(j4*16 + c)*65 + tt];
              if (v < worst){
                u32 tv = v;
                #pragma unroll
                for (int jj=0;jj<16;jj++){
                  u32 a = lst[jj];
                  u32 mn = tv < a ? tv : a;
                  u32 mx = tv < a ? a : tv;
                  lst[jj] = mn; tv = mx;
                }
                worst = lst[15];
              }
            }
          }
        }
      }
      __syncthreads();
    }
  }
  // cross-wave pair merge: waves (2k, 2k+1) share tokens wm..wm+63.
  // odd wave publishes its sorted-16; even wave merges (ascending src,
  // early-exit) and writes the single list for (token, slice s).
  {
    u32* shl = (u32*)usm;   // [2][64][16] — tiles/cand dead after last barrier
    if (wave & 1){
      u32* dst = shl + (((wave>>1)*64 + lane)*16);
      #pragma unroll
      for (int j=0;j<16;j++) dst[j] = lst[j];
    }
    __syncthreads();
    if (!(wave & 1)){
      const u32* src = shl + (((wave>>1)*64 + lane)*16);
      u32 worst = lst[15];
      for (int j=0;j<16;j++){
        u32 v = src[j];
        if (v >= worst) break;       // src ascending -> rest can't qualify
        u32 tv = v;
        #pragma unroll
        for (int jj=0;jj<16;jj++){
          u32 a = lst[jj];
          u32 mn = tv < a ? tv : a;
          u32 mx = tv < a ? a : tv;
          lst[jj] = mn; tv = mx;
        }
        worst = lst[15];
      }
      u32* dst = plist + ((size_t)(t0 + wm + lane)*NLIST + s)*16;
      #pragma unroll
      for (int j=0;j<16;j++) dst[j] = lst[j];
    }
  }
}

// ---- fused: merge NLIST lists/token (wave-parallel), vectorized gather, log0 ----
__global__ __launch_bounds__(256) void gather_log0(
    const u32* __restrict__ plist, const u16* __restrict__ memb, u16* __restrict__ out)
{
  __shared__ u32 keysh[NLIST*16];            // 256 keys
  __shared__ float wsh[KTOP]; __shared__ int ish[KTOP];
  int n = blockIdx.x, tid = threadIdx.x;
  keysh[tid & 255] = plist[(size_t)n*NLIST*16 + (tid & 255)];
  __syncthreads();
  if (tid < 64){
    // lane l<NLIST owns sorted list l; 16 rounds of wave-min; keys unique
    int ptr = 0;
    u32 head = (tid < NLIST) ? keysh[tid*16] : 0xFFFFFFFFu;
    for (int j=0;j<KTOP;j++){
      u32 m = head;
      #pragma unroll
      for (int o=32;o;o>>=1){
        u32 v = (u32)__shfl_xor((int)m, o);
        m = v < m ? v : m;
      }
      if (head == m && tid < NLIST){
        ptr++;
        head = (ptr < 16) ? keysh[tid*16 + ptr] : 0xFFFFFFFFu;
      }
      if (tid == 0){
        wsh[j] = exp2f(-__uint_as_float(m & 0xFFFFE000u));   // exp(-d), log2 key
        ish[j] = (int)(m & 0x1FFFu);
      }
    }
  }
  __syncthreads();
  // vectorized gather: thread t<96 owns elems [t*8, t*8+8) of the 768-row
  float v[8] = {};
  if (tid < 96){
    #pragma unroll
    for (int k=0;k<KTOP;k++){
      bf16x8 rv = *(const bf16x8*)(memb + (size_t)ish[k]*HDIM + tid*8);
      float wk = wsh[k];
      #pragma unroll
      for (int j=0;j<8;j++) v[j] = fmaf(wk, bf2f((u16)rv[j]), v[j]);
    }
  }
  float ssl = 0.f;
  #pragma unroll
  for (int j=0;j<8;j++) ssl += v[j]*v[j];
  float ss = block_sum(ssl);           // threads >=96 contribute 0
  float nn = sqrtf(ss);
  float nc = fminf(fmaxf(nn, 1e-5f), 1.0f-1e-5f);
  float sc = atanhf(nc)/nc;
  if (tid < 96){
    u16 ov[8];
    #pragma unroll
    for (int j=0;j<8;j++) ov[j] = f2bf(v[j]*sc);
    *(bf16x8*)(out + (size_t)n*HDIM + tid*8) = *(const bf16x8*)ov;
  }
}

extern "C" void kernel_launch(void* const* d_in, const int* in_sizes, int n_in,
                              void* d_out, int out_size, void* d_ws, size_t ws_size,
                              hipStream_t stream)
{
  const float* x    = (const float*)d_in[0];
  const float* ew1  = (const float*)d_in[1];
  const float* eb1  = (const float*)d_in[2];
  const float* eg   = (const float*)d_in[3];
  const float* ebe  = (const float*)d_in[4];
  const float* ew2  = (const float*)d_in[5];
  const float* eb2  = (const float*)d_in[6];
  const float* dw1  = (const float*)d_in[7];
  const float* db1  = (const float*)d_in[8];
  const float* dg   = (const float*)d_in[9];
  const float* dbe  = (const float*)d_in[10];
  const float* dw2  = (const float*)d_in[11];
  const float* db2  = (const float*)d_in[12];
  const float* mem  = (const float*)d_in[13];
  const float* imp  = (const float*)d_in[14];

  const size_t NE = (size_t)N_TOK*HDIM;       // 6,291,456
  float* out0 = (float*)d_out;                // fp32 output 0
  float* out1 = out0 + NE;                    // fp32 output 1 (pattern)
  u16* patb = (u16*)d_out;                    // bf16 pattern, inside output0 range
  const size_t SWE = (size_t)HDIM*H2DIM;
  u16* w1t  = (u16*)d_out + NE;
  u16* w2t  = w1t + SWE;
  u16* w1td = w1t + 2*SWE;
  u16* w2td = w1t + 3*SWE;                    // ends < output0 end

  char* w = (char*)d_ws;
  size_t off = 0;
  u16* vbuf = (u16*)(w+off); off += NE*2;                    // bf16; also h2 alias
  u16* h1b  = (u16*)(w+off); off += (size_t)N_TOK*H2DIM*2;   // bf16; ln_gelu in-place
  u16* memb = h1b;                                            // alias: live enc-end..gather
  float* a2f = (float*)(w+off); off += (size_t)N_TOK*4;
  float* iva = (float*)(w+off); off += (size_t)N_TOK*4;
  off = (off+15)&~(size_t)15;
  float4* pmeta = (float4*)(w+off); off += (size_t)PMEM*16;
  u32* plist = (u32*)(w+off); off += (size_t)N_TOK*NLIST*16*4;  // 8.4 MB
  (void)in_sizes; (void)n_in; (void)out_size; (void)ws_size;

  dim3 blk(256);
  transpose4_f2b<<<dim3(H2DIM/32, HDIM/32, 4), blk, 0, stream>>>(
      ew1, w1t, ew2, w2t, dw1, w1td, dw2, w2td);
  // encoder
  log0_rows<<<N_TOK, blk, 0, stream>>>(x, vbuf);
  gemm_bt<<<dim3(H2DIM/128, N_TOK/128), blk, 0, stream>>>(vbuf, w1t, eb1, h1b, N_TOK, H2DIM, HDIM);
  ln_gelu<<<N_TOK, blk, 0, stream>>>(h1b, eg, ebe, h1b);
  gemm_bt<<<dim3(HDIM/128, N_TOK/128), blk, 0, stream>>>(h1b, w2t, eb2, vbuf, N_TOK, HDIM, H2DIM);
  exp0_rows<<<N_TOK, blk, 0, stream>>>(vbuf, out1, patb, a2f, iva);
  // retrieval (memb aliases h1b — dead between encoder and decoder)
  prep_mem<<<PMEM, blk, 0, stream>>>(mem, imp, memb, pmeta);
  dist_topk<<<dim3(N_TOK/128, DSPLIT), blk, 0, stream>>>(patb, memb, a2f, iva, pmeta, plist);
  gather_log0<<<N_TOK, blk, 0, stream>>>(plist, memb, vbuf);
  // decoder
  gemm_bt<<<dim3(H2DIM/128, N_TOK/128), blk, 0, stream>>>(vbuf, w1td, db1, h1b, N_TOK, H2DIM, HDIM);
  ln_gelu<<<N_TOK, blk, 0, stream>>>(h1b, dg, dbe, h1b);
  gemm_bt<<<dim3(HDIM/128, N_TOK/128), blk, 0, stream>>>(h1b, w2td, db2, vbuf, N_TOK, HDIM, H2DIM);
  exp0_rows<<<N_TOK, blk, 0, stream>>>(vbuf, out0, nullptr, nullptr, nullptr);
}